// Round 21
// baseline (594.346 us; speedup 1.0000x reference)
//
#include <hip/hip_runtime.h>

#define HW 4096
#define CCH 256

typedef __bf16 bf16x8 __attribute__((ext_vector_type(8)));
typedef float f32x4 __attribute__((ext_vector_type(4)));
typedef float f32x2 __attribute__((ext_vector_type(2)));
typedef unsigned u32x2 __attribute__((ext_vector_type(2)));
typedef unsigned u32x4 __attribute__((ext_vector_type(4)));
typedef unsigned short u16;

// LDS row swizzle: spreads 8 ways even when rows step by 4
#define SWZ8(r) ((((r) + ((r) >> 2)) & 7) << 3)

__device__ __forceinline__ u16 f2b(float f) {
  union { __bf16 h; u16 u; } c; c.h = (__bf16)f; return c.u;   // v_cvt (RNE)
}
__device__ __forceinline__ unsigned f2b2(float a, float b) {
  union { __bf16 h[2]; unsigned u; } c;                        // v_cvt_pk_bf16_f32
  c.h[0] = (__bf16)a; c.h[1] = (__bf16)b; return c.u;
}
__device__ __forceinline__ float b2f(u16 h) {
  union { unsigned u; float f; } v; v.u = ((unsigned)h) << 16; return v.f;
}
__device__ __forceinline__ void nt_store4(const float4& v, float* p) {
  f32x4 t; t[0] = v.x; t[1] = v.y; t[2] = v.z; t[3] = v.w;
  __builtin_nontemporal_store(t, reinterpret_cast<f32x4*>(p));
}

// ---------------- Kernel P: fragment-major bf16 weight relayouts ----------------
__global__ __launch_bounds__(256) void kprep(
    const float* __restrict__ qkv_w, const float* __restrict__ out_w,
    const float* __restrict__ ca_w1, const float* __restrict__ ca_w2,
    u16* __restrict__ wq2, u16* __restrict__ wo2,
    u16* __restrict__ c1f, u16* __restrict__ c2f)
{
  int i = blockIdx.x * 256 + threadIdx.x;
  int j = i & 7, lane = (i >> 3) & 63, l15 = lane & 15, lg = lane >> 4;
  if (i < 48 * 8 * 512) {                      // qkv: 48 n-tiles, K=256 (8 kb)
    int kb = (i >> 9) & 7, T = i >> 12;
    wq2[i] = f2b(qkv_w[(kb * 32 + lg * 8 + j) * 768 + T * 16 + l15]);
  }
  if (i < 16 * 8 * 512) {                      // out: 16 n-tiles, K=256
    int kb = (i >> 9) & 7, T = i >> 12;
    wo2[i] = f2b(out_w[(kb * 32 + lg * 8 + j) * 256 + T * 16 + l15]);
  }
  if (i < 4 * 8 * 512) {                       // ca_w1: 4 n-tiles (n<64), K=256
    int kb = (i >> 9) & 7, T = i >> 12;
    c1f[i] = f2b(ca_w1[(kb * 32 + lg * 8 + j) * 64 + T * 16 + l15]);
  }
  if (i < 16 * 2 * 512) {                      // ca_w2: 16 n-tiles, K=64 (2 kb)
    int kb = (i >> 9) & 1, T = i >> 10;
    c2f[i] = f2b(ca_w2[(kb * 32 + lg * 8 + j) * 256 + T * 16 + l15]);
  }
}

// ---------------- Kernel G: stage + CA-gate; emits x2w init + xg fragments ----------------
// 40 KB LDS (pX + pH), 4 blocks/CU. xgf layout: [win][wv][kb][lane][8] u16.
__global__ __launch_bounds__(256, 4) void kg_gate(
    const float* __restrict__ x, u16* __restrict__ x2w, u16* __restrict__ xgf,
    const float* __restrict__ out_b,
    const u16* __restrict__ c1f, const float* __restrict__ ca_b1,
    const u16* __restrict__ c2f, const float* __restrict__ ca_b2)
{
  __shared__ u16 smem[20480];          // 40 KB
  u16* pX = smem;                      // [64][256] x -> xg      (32 KB)
  u16* pH = smem + 16384;              // [64][64] hidden H      ( 8 KB)

  const int tid = threadIdx.x;
  const int lane = tid & 63;
  const int wv = __builtin_amdgcn_readfirstlane(tid >> 6);
  const int l15 = lane & 15;
  const int lg = lane >> 4;

  const int bid = blockIdx.x;
  const int wid = (bid & 7) * 256 + (bid >> 3);   // XCD-chunked
  const int b = wid >> 6, wrem = wid & 63;
  const int pbase = (wrem >> 3) * (8 * 64) + (wrem & 7) * 8;
  const float* ximg = x + (size_t)b * CCH * HW;

  const int tokA = wv * 16 + l15;          // wave strip row
  const int swA = SWZ8(tokA);

  // ---- stage raw x -> pX via float4 ----
  {
    const int t0 = l15 * 4;
    const int prow = pbase + (l15 >> 1) * 64 + (l15 & 1) * 4;
    #pragma unroll 2
    for (int i = 0; i < 16; ++i) {
      int c = i * 16 + wv * 4 + lg;
      const float4 v = *reinterpret_cast<const float4*>(&ximg[(size_t)c * HW + prow]);
      pX[(t0 + 0) * 256 + (c ^ SWZ8(t0 + 0))] = f2b(v.x);
      pX[(t0 + 1) * 256 + (c ^ SWZ8(t0 + 1))] = f2b(v.y);
      pX[(t0 + 2) * 256 + (c ^ SWZ8(t0 + 2))] = f2b(v.z);
      pX[(t0 + 3) * 256 + (c ^ SWZ8(t0 + 3))] = f2b(v.w);
    }
  }
  __syncthreads();

  // ---- channel-attention gating; xg overwrites x in pX; gate kept in regs ----
  uint2 gpk[16];                       // bf16-pair gate values per n-tile (32 VGPR)
  {
    bf16x8 aXr[8];
    #pragma unroll
    for (int kb = 0; kb < 8; ++kb)
      aXr[kb] = *reinterpret_cast<const bf16x8*>(&pX[tokA * 256 + ((kb * 32 + lg * 8) ^ swA)]);
    // layer1 (swapped): C row = n1, col = token -> packed pH write
    #pragma unroll
    for (int nt1 = 0; nt1 < 4; ++nt1) {
      f32x4 c1 = {0.f, 0.f, 0.f, 0.f};
      #pragma unroll
      for (int kb = 0; kb < 8; ++kb) {
        bf16x8 bw = *reinterpret_cast<const bf16x8*>(&c1f[(nt1 * 8 + kb) * 512 + lane * 8]);
        c1 = __builtin_amdgcn_mfma_f32_16x16x32_bf16(bw, aXr[kb], c1, 0, 0, 0);
      }
      const float4 b14 = *reinterpret_cast<const float4*>(&ca_b1[nt1 * 16 + lg * 4]);
      uint2 pk;
      pk.x = f2b2(fmaxf(c1[0] + b14.x, 0.f), fmaxf(c1[1] + b14.y, 0.f));
      pk.y = f2b2(fmaxf(c1[2] + b14.z, 0.f), fmaxf(c1[3] + b14.w, 0.f));
      int d0 = nt1 * 16 + lg * 4;
      *reinterpret_cast<uint2*>(&pH[tokA * 64 + (d0 ^ swA)]) = pk;
    }
    bf16x8 hB[2];
    #pragma unroll
    for (int kb = 0; kb < 2; ++kb)
      hB[kb] = *reinterpret_cast<const bf16x8*>(&pH[tokA * 64 + ((kb * 32 + lg * 8) ^ swA)]);
    #pragma unroll
    for (int nt = 0; nt < 16; ++nt) {
      f32x4 a2 = {0.f, 0.f, 0.f, 0.f};
      #pragma unroll
      for (int kb = 0; kb < 2; ++kb) {
        bf16x8 w2a = *reinterpret_cast<const bf16x8*>(&c2f[(nt * 2 + kb) * 512 + lane * 8]);
        a2 = __builtin_amdgcn_mfma_f32_16x16x32_bf16(w2a, hB[kb], a2, 0, 0, 0);
      }
      const int n0 = nt * 16 + lg * 4;
      const float4 b24 = *reinterpret_cast<const float4*>(&ca_b2[n0]);
      const ushort4 xq = *reinterpret_cast<const ushort4*>(&pX[tokA * 256 + (n0 ^ swA)]);
      float xg0 = b2f(xq.x) / (1.f + __expf(-(a2[0] + b24.x)));
      float xg1 = b2f(xq.y) / (1.f + __expf(-(a2[1] + b24.y)));
      float xg2 = b2f(xq.z) / (1.f + __expf(-(a2[2] + b24.z)));
      float xg3 = b2f(xq.w) / (1.f + __expf(-(a2[3] + b24.w)));
      uint2 pk;
      pk.x = f2b2(xg0, xg1);
      pk.y = f2b2(xg2, xg3);
      gpk[nt] = pk;
      *reinterpret_cast<uint2*>(&pX[tokA * 256 + (n0 ^ swA)]) = pk;
    }
  }

  // ---- x2w init = bf16(xg + out_b) : 16 transposed uint2 NT stores ----
  {
    u16* wout = x2w + (size_t)wid * 16384;
    #pragma unroll
    for (int nt0 = 0; nt0 < 4; ++nt0) {
      #pragma unroll
      for (int r = 0; r < 4; ++r) {
        int cq = nt0 * 16 + lg * 4 + r;
        unsigned v0 = (r < 2) ? (gpk[nt0     ].x >> (16 * r)) : (gpk[nt0     ].y >> (16 * (r - 2)));
        unsigned v1 = (r < 2) ? (gpk[nt0 +  4].x >> (16 * r)) : (gpk[nt0 +  4].y >> (16 * (r - 2)));
        unsigned v2 = (r < 2) ? (gpk[nt0 +  8].x >> (16 * r)) : (gpk[nt0 +  8].y >> (16 * (r - 2)));
        unsigned v3 = (r < 2) ? (gpk[nt0 + 12].x >> (16 * r)) : (gpk[nt0 + 12].y >> (16 * (r - 2)));
        u32x2 o;
        o[0] = f2b2(b2f((u16)v0) + out_b[cq],       b2f((u16)v1) + out_b[cq + 64]);
        o[1] = f2b2(b2f((u16)v2) + out_b[cq + 128], b2f((u16)v3) + out_b[cq + 192]);
        __builtin_nontemporal_store(o, reinterpret_cast<u32x2*>(&wout[cq * 256 + tokA * 4]));
      }
    }
  }

  // ---- store xg A-fragments (own strip) frag-major: 8 x 16B NT stores ----
  {
    u16* xo = xgf + ((size_t)wid * 4 + wv) * 4096;   // per (win, wave): 8 kb x 512 u16
    #pragma unroll
    for (int kb = 0; kb < 8; ++kb) {
      union { bf16x8 v; u32x4 u; } c;
      c.v = *reinterpret_cast<const bf16x8*>(&pX[tokA * 256 + ((kb * 32 + lg * 8) ^ swA)]);
      __builtin_nontemporal_store(c.u, reinterpret_cast<u32x4*>(&xo[kb * 512 + lane * 8]));
    }
  }
}

// ---------------- Kernel A: windowed MHSA head loop (24 KB LDS, 6 blocks/CU) ----------------
__global__ __launch_bounds__(256, 6) void ka_attn(
    const u16* __restrict__ xgf, u16* __restrict__ Og,
    const u16* __restrict__ wq2, const float* __restrict__ qkv_b)
{
  __shared__ u16 smem[12288];          // 24 KB
  u16* pQ  = smem;                     // [64][64] Q -> P
  u16* pK  = smem + 4096;              // [64][64] K
  u16* pVT = smem + 8192;              // [64][64] V^T

  const int tid = threadIdx.x;
  const int lane = tid & 63;
  const int wv = __builtin_amdgcn_readfirstlane(tid >> 6);
  const int l15 = lane & 15;
  const int lg = lane >> 4;

  const int bid = blockIdx.x;
  const int wid = (bid & 7) * 256 + (bid >> 3);   // XCD-chunked (matches kg_gate)
  const int tokA = wv * 16 + l15;
  const int swA = SWZ8(tokA);

  // ---- load xg A-fragments (coalesced, L2-hot from kg_gate) ----
  bf16x8 aG[8];
  {
    const u16* xi = xgf + ((size_t)wid * 4 + wv) * 4096;
    #pragma unroll
    for (int kb = 0; kb < 8; ++kb)
      aG[kb] = *reinterpret_cast<const bf16x8*>(&xi[kb * 512 + lane * 8]);
  }

  u16* ogw = Og + (size_t)wid * 16384;

  for (int h = 0; h < 4; ++h) {
    // ---------- QKV (swapped): C row = out-ch, col = token; packed Q/K writes ----------
    #pragma unroll 2
    for (int tau = 0; tau < 12; ++tau) {
      int kind = tau >> 2, sub = tau & 3;
      int colbase = kind * 256 + h * 64 + sub * 16;
      int T = kind * 16 + h * 4 + sub;
      f32x4 acc = {0.f, 0.f, 0.f, 0.f};
      #pragma unroll
      for (int kb = 0; kb < 8; ++kb) {
        bf16x8 bw = *reinterpret_cast<const bf16x8*>(&wq2[(T * 8 + kb) * 512 + lane * 8]);
        acc = __builtin_amdgcn_mfma_f32_16x16x32_bf16(bw, aG[kb], acc, 0, 0, 0);
      }
      const float4 bia4 = *reinterpret_cast<const float4*>(&qkv_b[colbase + lg * 4]);
      if (kind == 2) {
        #pragma unroll
        for (int r = 0; r < 4; ++r) {
          int d = sub * 16 + lg * 4 + r;
          float bv = (r == 0) ? bia4.x : (r == 1) ? bia4.y : (r == 2) ? bia4.z : bia4.w;
          pVT[d * 64 + (tokA ^ ((d & 7) << 3))] = f2b(acc[r] + bv);
        }
      } else {
        uint2 pk;
        pk.x = f2b2(acc[0] + bia4.x, acc[1] + bia4.y);
        pk.y = f2b2(acc[2] + bia4.z, acc[3] + bia4.w);
        int d0 = sub * 16 + lg * 4;
        u16* dst = (kind == 0) ? pQ : pK;
        *reinterpret_cast<uint2*>(&dst[tokA * 64 + (d0 ^ swA)]) = pk;
      }
    }
    __syncthreads();

    // ---------- scores S = Q @ K^T (strip rows) ----------
    bf16x8 aQ[2];
    #pragma unroll
    for (int kb = 0; kb < 2; ++kb)
      aQ[kb] = *reinterpret_cast<const bf16x8*>(&pQ[tokA * 64 + ((kb * 32 + lg * 8) ^ swA)]);
    f32x4 s4[4];
    #pragma unroll
    for (int jt = 0; jt < 4; ++jt) {
      int krow = jt * 16 + l15;
      int swk = SWZ8(krow);
      f32x4 acc = {0.f, 0.f, 0.f, 0.f};
      #pragma unroll
      for (int kb = 0; kb < 2; ++kb) {
        bf16x8 bK = *reinterpret_cast<const bf16x8*>(&pK[krow * 64 + ((kb * 32 + lg * 8) ^ swk)]);
        acc = __builtin_amdgcn_mfma_f32_16x16x32_bf16(aQ[kb], bK, acc, 0, 0, 0);
      }
      s4[jt] = acc;
    }
    // ---------- softmax per row, P overwrites own pQ strip ----------
    #pragma unroll
    for (int r = 0; r < 4; ++r) {
      float m = fmaxf(fmaxf(s4[0][r], s4[1][r]), fmaxf(s4[2][r], s4[3][r]));
      #pragma unroll
      for (int off = 1; off < 16; off <<= 1) m = fmaxf(m, __shfl_xor(m, off));
      float e0 = __expf((s4[0][r] - m) * 0.125f);
      float e1 = __expf((s4[1][r] - m) * 0.125f);
      float e2 = __expf((s4[2][r] - m) * 0.125f);
      float e3 = __expf((s4[3][r] - m) * 0.125f);
      float sum = e0 + e1 + e2 + e3;
      #pragma unroll
      for (int off = 1; off < 16; off <<= 1) sum += __shfl_xor(sum, off);
      float is = 1.f / sum;
      int tok = wv * 16 + lg * 4 + r;
      int swp = SWZ8(tok);
      pQ[tok * 64 + ((     l15) ^ swp)] = f2b(e0 * is);
      pQ[tok * 64 + ((16 + l15) ^ swp)] = f2b(e1 * is);
      pQ[tok * 64 + ((32 + l15) ^ swp)] = f2b(e2 * is);
      pQ[tok * 64 + ((48 + l15) ^ swp)] = f2b(e3 * is);
    }
    // ---------- PV: O^T = V^T @ P^T (strip-private) ----------
    bf16x8 bP[2];
    #pragma unroll
    for (int kb = 0; kb < 2; ++kb)
      bP[kb] = *reinterpret_cast<const bf16x8*>(&pQ[tokA * 64 + ((kb * 32 + lg * 8) ^ swA)]);
    #pragma unroll
    for (int dt = 0; dt < 4; ++dt) {
      int drow = dt * 16 + l15;
      int swd = (drow & 7) << 3;
      f32x4 acc = {0.f, 0.f, 0.f, 0.f};
      #pragma unroll
      for (int kb = 0; kb < 2; ++kb) {
        bf16x8 aV = *reinterpret_cast<const bf16x8*>(&pVT[drow * 64 + ((kb * 32 + lg * 8) ^ swd)]);
        acc = __builtin_amdgcn_mfma_f32_16x16x32_bf16(aV, bP[kb], acc, 0, 0, 0);
      }
      int d0 = h * 64 + dt * 16 + lg * 4;
      uint2 pk;
      pk.x = f2b2(acc[0], acc[1]);
      pk.y = f2b2(acc[2], acc[3]);
      *reinterpret_cast<uint2*>(&ogw[(d0 >> 2) * 256 + tokA * 4]) = pk;
    }
    __syncthreads();
  }
}

// ---------------- Kernel A2: out-proj GEMM, x2w += O @ Wout (bf16 RMW) ----------------
__global__ __launch_bounds__(256, 3) void kb_oproj(
    const u16* __restrict__ Og, const u16* __restrict__ wo2,
    u16* __restrict__ x2w)
{
  const int tid = threadIdx.x;
  const int lane = tid & 63;
  const int wv = __builtin_amdgcn_readfirstlane(tid >> 6);
  const int l15 = lane & 15;
  const int lg = lane >> 4;
  const int bid = blockIdx.x;
  const int wid = (bid & 7) * 256 + (bid >> 3);   // XCD-chunked (matches ka_attn)
  const int tokA = wv * 16 + l15;

  const u16* og = Og + (size_t)wid * 16384;
  bf16x8 bO[8];
  #pragma unroll
  for (int kb = 0; kb < 8; ++kb) {
    int dq = kb * 8 + lg * 2;
    uint2 lo = *reinterpret_cast<const uint2*>(&og[dq * 256 + tokA * 4]);
    uint2 hi = *reinterpret_cast<const uint2*>(&og[(dq + 1) * 256 + tokA * 4]);
    union { uint4 u; bf16x8 v; } cvt;
    cvt.u.x = lo.x; cvt.u.y = lo.y; cvt.u.z = hi.x; cvt.u.w = hi.y;
    bO[kb] = cvt.v;
  }

  f32x4 acc[16];
  #pragma unroll
  for (int nt = 0; nt < 16; ++nt) {
    f32x4 z = {0.f, 0.f, 0.f, 0.f};
    acc[nt] = z;
  }
  #pragma unroll
  for (int nt = 0; nt < 16; ++nt) {
    #pragma unroll
    for (int kb = 0; kb < 8; ++kb) {
      bf16x8 wA = *reinterpret_cast<const bf16x8*>(&wo2[(nt * 8 + kb) * 512 + lane * 8]);
      acc[nt] = __builtin_amdgcn_mfma_f32_16x16x32_bf16(wA, bO[kb], acc[nt], 0, 0, 0);
    }
  }

  u16* wout = x2w + (size_t)wid * 16384;
  #pragma unroll
  for (int nt0 = 0; nt0 < 4; ++nt0) {
    #pragma unroll
    for (int r = 0; r < 4; ++r) {
      int cq = nt0 * 16 + lg * 4 + r;
      u16* p = &wout[cq * 256 + tokA * 4];
      uint2 cur = *reinterpret_cast<const uint2*>(p);
      float c0 = b2f((u16)(cur.x & 0xffff)) + acc[nt0     ][r];
      float c1 = b2f((u16)(cur.x >> 16))    + acc[nt0 +  4][r];
      float c2 = b2f((u16)(cur.y & 0xffff)) + acc[nt0 +  8][r];
      float c3 = b2f((u16)(cur.y >> 16))    + acc[nt0 + 12][r];
      uint2 o;
      o.x = f2b2(c0, c1);
      o.y = f2b2(c2, c3);
      *reinterpret_cast<uint2*>(p) = o;
    }
  }
}

// ---------------- Kernel C: grouped conv1 + BN + ReLU (bf16 in, bf16 out) ----------------
__global__ __launch_bounds__(256) void kc_conv1(
    const u16* __restrict__ x2w, const float* __restrict__ w1, const float* __restrict__ b1,
    const float* __restrict__ g1, const float* __restrict__ bb1,
    const float* __restrict__ m1, const float* __restrict__ v1,
    u16* __restrict__ y1)
{
  __shared__ float sin_[4 * 22 * 72];
  const int bid = blockIdx.x;
  const int wid = (bid & 7) * 1024 + (bid >> 3);     // XCD-chunked
  int b = wid >> 8, rem = wid & 255, j = rem >> 2, qt = rem & 3;
  const u16* xw = x2w + (size_t)b * 64 * 16384;
  for (int idx = threadIdx.x; idx < 22 * 70; idx += 256) {
    int yy = idx / 70, xx = idx - yy * 70;
    int ih = qt * 16 + yy - 3, iw = xx - 3;
    uint2 v = {0u, 0u};
    if (ih >= 0 && ih < 64 && iw >= 0 && iw < 64) {
      int wr = (ih >> 3) * 8 + (iw >> 3);
      int tok = (ih & 7) * 8 + (iw & 7);
      v = *reinterpret_cast<const uint2*>(&xw[(size_t)wr * 16384 + j * 256 + tok * 4]);
    }
    sin_[0 * 1584 + yy * 72 + xx] = b2f((u16)(v.x & 0xffff));
    sin_[1 * 1584 + yy * 72 + xx] = b2f((u16)(v.x >> 16));
    sin_[2 * 1584 + yy * 72 + xx] = b2f((u16)(v.y & 0xffff));
    sin_[3 * 1584 + yy * 72 + xx] = b2f((u16)(v.y >> 16));
  }
  __syncthreads();

  float inv = g1[j] / sqrtf(v1[j] + 1e-5f);
  float shf = bb1[j] - m1[j] * inv;
  float bia = b1[j];
  u16* yo = y1 + ((size_t)b * 64 + j) * HW + qt * 16 * 64;
  const float* wbase = w1 + j * 4 * 49;

  int y = threadIdx.x >> 4, x4 = (threadIdx.x & 15) * 4;
  float a0 = 0.f, a1 = 0.f, a2 = 0.f, a3 = 0.f;
  for (int i = 0; i < 4; ++i) {
    #pragma unroll
    for (int ky = 0; ky < 7; ++ky) {
      const float* row = sin_ + (i * 22 + y + ky) * 72 + x4;
      const f32x4 p0 = *reinterpret_cast<const f32x4*>(row);
      const f32x4 p1 = *reinterpret_cast<const f32x4*>(row + 4);
      const f32x2 p2 = *reinterpret_cast<const f32x2*>(row + 8);
      float v[10] = {p0[0], p0[1], p0[2], p0[3], p1[0], p1[1], p1[2], p1[3], p2[0], p2[1]};
      const float* wr = wbase + (i * 7 + ky) * 7;
      #pragma unroll
      for (int kx = 0; kx < 7; ++kx) {
        float wvv = wr[kx];
        a0 += v[kx] * wvv; a1 += v[kx+1] * wvv;
        a2 += v[kx+2] * wvv; a3 += v[kx+3] * wvv;
      }
    }
  }
  u32x2 o;
  o[0] = f2b2(fmaxf((a0 + bia) * inv + shf, 0.f), fmaxf((a1 + bia) * inv + shf, 0.f));
  o[1] = f2b2(fmaxf((a2 + bia) * inv + shf, 0.f), fmaxf((a3 + bia) * inv + shf, 0.f));
  __builtin_nontemporal_store(o, reinterpret_cast<u32x2*>(yo + y * 64 + x4));
}

// ---------------- Kernel D: grouped conv2 + BN + sigmoid gate * x2w (bf16) ----------------
__global__ __launch_bounds__(256) void kd_conv2(
    const u16* __restrict__ y1, const u16* __restrict__ x2w,
    const float* __restrict__ w2, const float* __restrict__ b2,
    const float* __restrict__ g2, const float* __restrict__ bb2,
    const float* __restrict__ m2, const float* __restrict__ v2,
    float* __restrict__ out)
{
  __shared__ float sin_[70 * 72];
  const int bid = blockIdx.x;
  const int wid = (bid & 7) * 256 + (bid >> 3);      // XCD-chunked
  int b = wid >> 6, g = wid & 63;
  const u16* yin = y1 + ((size_t)b * 64 + g) * HW;

  // zero halo: rows 0-2 & 67-69 (full), cols {0,1,2,67,68,69} of rows 3..66
  for (int idx = threadIdx.x; idx < 6 * 72; idx += 256) {
    int r = idx / 72, c = idx - r * 72;
    sin_[(r < 3 ? r : 64 + r) * 72 + c] = 0.f;
  }
  for (int idx = threadIdx.x; idx < 64 * 6; idx += 256) {
    int r = idx / 6, c = idx - r * 6;
    sin_[(r + 3) * 72 + (c < 3 ? c : 64 + c)] = 0.f;
  }
  // interior: uint2 global loads (4 bf16), scalar LDS writes
  for (int idx = threadIdx.x; idx < 64 * 16; idx += 256) {
    int r = idx >> 4, c4 = (idx & 15) * 4;
    uint2 v = *reinterpret_cast<const uint2*>(&yin[r * 64 + c4]);
    float* d = &sin_[(r + 3) * 72 + 3 + c4];
    d[0] = b2f((u16)(v.x & 0xffff)); d[1] = b2f((u16)(v.x >> 16));
    d[2] = b2f((u16)(v.y & 0xffff)); d[3] = b2f((u16)(v.y >> 16));
  }
  __syncthreads();

  float inv[4], shf[4], bia[4];
  #pragma unroll
  for (int i = 0; i < 4; ++i) {
    int n = 4 * g + i;
    float sc = g2[n] / sqrtf(v2[n] + 1e-5f);
    inv[i] = sc; shf[i] = bb2[n] - m2[n] * sc; bia[i] = b2[n];
  }
  const float* wb = w2 + 4 * g * 49;
  const u16* xw = x2w + (size_t)b * 64 * 16384;

  for (int it = 0; it < 4; ++it) {
    int s = it * 256 + threadIdx.x;
    int y = s >> 4, x4 = (s & 15) * 4;
    float acc[4][4] = {};
    #pragma unroll
    for (int ky = 0; ky < 7; ++ky) {
      const float* row = sin_ + (y + ky) * 72 + x4;
      const f32x4 p0 = *reinterpret_cast<const f32x4*>(row);
      const f32x4 p1 = *reinterpret_cast<const f32x4*>(row + 4);
      const f32x2 p2 = *reinterpret_cast<const f32x2*>(row + 8);
      float v[10] = {p0[0], p0[1], p0[2], p0[3], p1[0], p1[1], p1[2], p1[3], p2[0], p2[1]};
      #pragma unroll
      for (int i = 0; i < 4; ++i) {
        const float* wr = wb + i * 49 + ky * 7;
        #pragma unroll
        for (int kx = 0; kx < 7; ++kx) {
          float wvv = wr[kx];
          acc[i][0] += v[kx] * wvv; acc[i][1] += v[kx+1] * wvv;
          acc[i][2] += v[kx+2] * wvv; acc[i][3] += v[kx+3] * wvv;
        }
      }
    }
    int po = y * 64 + x4;
    int wr_ = (y >> 3) * 8 + (x4 >> 3);
    int t0 = (y & 7) * 8 + (x4 & 7);
    const u16* gp = &xw[(size_t)wr_ * 16384 + g * 256 + t0 * 4];
    uint2 q0 = *reinterpret_cast<const uint2*>(gp + 0);
    uint2 q1 = *reinterpret_cast<const uint2*>(gp + 4);
    uint2 q2 = *reinterpret_cast<const uint2*>(gp + 8);
    uint2 q3 = *reinterpret_cast<const uint2*>(gp + 12);
    #pragma unroll
    for (int i = 0; i < 4; ++i) {
      int n = 4 * g + i;
      float* op = out + ((size_t)b * 256 + n) * HW + po;
      float y0 = (acc[i][0] + bia[i]) * inv[i] + shf[i];
      float y1v = (acc[i][1] + bia[i]) * inv[i] + shf[i];
      float y2 = (acc[i][2] + bia[i]) * inv[i] + shf[i];
      float y3 = (acc[i][3] + bia[i]) * inv[i] + shf[i];
      float g0 = b2f((u16)(i < 2 ? (q0.x >> (16 * i)) : (q0.y >> (16 * (i - 2)))));
      float g1v = b2f((u16)(i < 2 ? (q1.x >> (16 * i)) : (q1.y >> (16 * (i - 2)))));
      float g2v = b2f((u16)(i < 2 ? (q2.x >> (16 * i)) : (q2.y >> (16 * (i - 2)))));
      float g3 = b2f((u16)(i < 2 ? (q3.x >> (16 * i)) : (q3.y >> (16 * (i - 2)))));
      float4 r;
      r.x = g0  / (1.f + __expf(-y0));
      r.y = g1v / (1.f + __expf(-y1v));
      r.z = g2v / (1.f + __expf(-y2));
      r.w = g3  / (1.f + __expf(-y3));
      nt_store4(r, op);
    }
  }
}

extern "C" void kernel_launch(void* const* d_in, const int* in_sizes, int n_in,
                              void* d_out, int out_size, void* d_ws, size_t ws_size,
                              hipStream_t stream) {
  const float* x     = (const float*)d_in[0];
  const float* qkv_w = (const float*)d_in[1];
  const float* qkv_b = (const float*)d_in[2];
  const float* out_w = (const float*)d_in[3];
  const float* out_b = (const float*)d_in[4];
  const float* ca_w1 = (const float*)d_in[5];
  const float* ca_b1 = (const float*)d_in[6];
  const float* ca_w2 = (const float*)d_in[7];
  const float* ca_b2 = (const float*)d_in[8];
  const float* sa_w1 = (const float*)d_in[9];
  const float* sa_b1 = (const float*)d_in[10];
  const float* bn1_g = (const float*)d_in[11];
  const float* bn1_b = (const float*)d_in[12];
  const float* bn1_m = (const float*)d_in[13];
  const float* bn1_v = (const float*)d_in[14];
  const float* sa_w2 = (const float*)d_in[15];
  const float* sa_b2 = (const float*)d_in[16];
  const float* bn2_g = (const float*)d_in[17];
  const float* bn2_b = (const float*)d_in[18];
  const float* bn2_m = (const float*)d_in[19];
  const float* bn2_v = (const float*)d_in[20];

  float* outp = (float*)d_out;
  u16* x2w = (u16*)d_ws;                            // [win][cq][tok][quad] bf16, 64 MB
  u16* y1 = x2w + (size_t)2048 * 16384;             // conv1 output bf16, 16 MB
  u16* xgf = y1 + (size_t)8 * 1024 * 1024;          // xg fragments, 64 MB

  // bf16 weights + O buffer stashed in d_out (overwritten by kd at the end)
  u16* wq2 = (u16*)d_out;                           // 196608
  u16* wo2 = wq2 + 48 * 8 * 512;                    // 65536
  u16* c1f = wo2 + 16 * 8 * 512;                    // 16384
  u16* c2f = c1f + 4 * 8 * 512;                     // 16384
  u16* Og  = c2f + 16 * 2 * 512;                    // 2048*16384 u16 = 64 MB

  kprep   <<<768,  256, 0, stream>>>(qkv_w, out_w, ca_w1, ca_w2, wq2, wo2, c1f, c2f);
  kg_gate <<<2048, 256, 0, stream>>>(x, x2w, xgf, out_b, c1f, ca_b1, c2f, ca_b2);
  ka_attn <<<2048, 256, 0, stream>>>(xgf, Og, wq2, qkv_b);
  kb_oproj<<<2048, 256, 0, stream>>>(Og, wo2, x2w);
  kc_conv1<<<8192, 256, 0, stream>>>(x2w, sa_w1, sa_b1, bn1_g, bn1_b, bn1_m, bn1_v, y1);
  kd_conv2<<<2048, 256, 0, stream>>>(y1, x2w, sa_w2, sa_b2, bn2_g, bn2_b, bn2_m, bn2_v, outp);
}

// Round 22
// 418.546 us; speedup vs baseline: 1.4200x; 1.4200x over previous
//
#include <hip/hip_runtime.h>

#define HW 4096
#define CCH 256

typedef __bf16 bf16x8 __attribute__((ext_vector_type(8)));
typedef float f32x4 __attribute__((ext_vector_type(4)));
typedef float f32x2 __attribute__((ext_vector_type(2)));
typedef unsigned u32x2 __attribute__((ext_vector_type(2)));
typedef unsigned short u16;

// LDS row swizzle: spreads 8 ways even when rows step by 4
#define SWZ8(r) ((((r) + ((r) >> 2)) & 7) << 3)

__device__ __forceinline__ u16 f2b(float f) {
  union { __bf16 h; u16 u; } c; c.h = (__bf16)f; return c.u;   // v_cvt (RNE)
}
__device__ __forceinline__ unsigned f2b2(float a, float b) {
  union { __bf16 h[2]; unsigned u; } c;                        // v_cvt_pk_bf16_f32
  c.h[0] = (__bf16)a; c.h[1] = (__bf16)b; return c.u;
}
__device__ __forceinline__ float b2f(u16 h) {
  union { unsigned u; float f; } v; v.u = ((unsigned)h) << 16; return v.f;
}
__device__ __forceinline__ void nt_store4(const float4& v, float* p) {
  f32x4 t; t[0] = v.x; t[1] = v.y; t[2] = v.z; t[3] = v.w;
  __builtin_nontemporal_store(t, reinterpret_cast<f32x4*>(p));
}

// ---------------- Kernel P: fragment-major bf16 weight relayouts ----------------
__global__ __launch_bounds__(256) void kprep(
    const float* __restrict__ qkv_w, const float* __restrict__ out_w,
    const float* __restrict__ ca_w1, const float* __restrict__ ca_w2,
    u16* __restrict__ wq2, u16* __restrict__ wo2,
    u16* __restrict__ c1f, u16* __restrict__ c2f)
{
  int i = blockIdx.x * 256 + threadIdx.x;
  int j = i & 7, lane = (i >> 3) & 63, l15 = lane & 15, lg = lane >> 4;
  if (i < 48 * 8 * 512) {                      // qkv: 48 n-tiles, K=256 (8 kb)
    int kb = (i >> 9) & 7, T = i >> 12;
    wq2[i] = f2b(qkv_w[(kb * 32 + lg * 8 + j) * 768 + T * 16 + l15]);
  }
  if (i < 16 * 8 * 512) {                      // out: 16 n-tiles, K=256
    int kb = (i >> 9) & 7, T = i >> 12;
    wo2[i] = f2b(out_w[(kb * 32 + lg * 8 + j) * 256 + T * 16 + l15]);
  }
  if (i < 4 * 8 * 512) {                       // ca_w1: 4 n-tiles (n<64), K=256
    int kb = (i >> 9) & 7, T = i >> 12;
    c1f[i] = f2b(ca_w1[(kb * 32 + lg * 8 + j) * 64 + T * 16 + l15]);
  }
  if (i < 16 * 2 * 512) {                      // ca_w2: 16 n-tiles, K=64 (2 kb)
    int kb = (i >> 9) & 1, T = i >> 10;
    c2f[i] = f2b(ca_w2[(kb * 32 + lg * 8 + j) * 256 + T * 16 + l15]);
  }
}

// ---------------- Kernel A: CA-gate + windowed MHSA (O to global) ----------------
// Swapped-operand MFMA epilogues: C = (row=out-ch, col=token) -> packed uint2
// LDS writes (consecutive d in the lane's own token row).
__global__ __launch_bounds__(256, 4) void kb_attn(
    const float* __restrict__ x, u16* __restrict__ x2w, u16* __restrict__ Og,
    const u16* __restrict__ wq2, const float* __restrict__ qkv_b,
    const float* __restrict__ out_b,
    const u16* __restrict__ c1f, const float* __restrict__ ca_b1,
    const u16* __restrict__ c2f, const float* __restrict__ ca_b2)
{
  __shared__ u16 smem[20480];          // 40 KB
  u16* pX  = smem;                     // [64][256] x -> xg      (32 KB, phase 1)
  u16* pH  = smem + 16384;             // [64][64] hidden H      ( 8 KB, phase 1)
  u16* pQ  = smem;                     // [64][64] Q -> P        (phase 2, aliases pX)
  u16* pK  = smem + 4096;              // [64][64] K
  u16* pVT = smem + 8192;              // [64][64] V^T

  const int tid = threadIdx.x;
  const int lane = tid & 63;
  const int wv = __builtin_amdgcn_readfirstlane(tid >> 6);
  const int l15 = lane & 15;
  const int lg = lane >> 4;

  const int bid = blockIdx.x;
  const int wid = (bid & 7) * 256 + (bid >> 3);   // XCD-chunked
  const int b = wid >> 6, wrem = wid & 63;
  const int pbase = (wrem >> 3) * (8 * 64) + (wrem & 7) * 8;
  const float* ximg = x + (size_t)b * CCH * HW;

  const int tokA = wv * 16 + l15;          // wave strip row
  const int swA = SWZ8(tokA);

  // ---- stage raw x -> pX via float4 ----
  {
    const int t0 = l15 * 4;
    const int prow = pbase + (l15 >> 1) * 64 + (l15 & 1) * 4;
    #pragma unroll 2
    for (int i = 0; i < 16; ++i) {
      int c = i * 16 + wv * 4 + lg;
      const float4 v = *reinterpret_cast<const float4*>(&ximg[(size_t)c * HW + prow]);
      pX[(t0 + 0) * 256 + (c ^ SWZ8(t0 + 0))] = f2b(v.x);
      pX[(t0 + 1) * 256 + (c ^ SWZ8(t0 + 1))] = f2b(v.y);
      pX[(t0 + 2) * 256 + (c ^ SWZ8(t0 + 2))] = f2b(v.z);
      pX[(t0 + 3) * 256 + (c ^ SWZ8(t0 + 3))] = f2b(v.w);
    }
  }
  __syncthreads();

  // ---- channel-attention gating; xg overwrites x in pX; gate kept in regs ----
  uint2 gpk[16];                       // bf16-pair gate values per n-tile (32 VGPR)
  {
    bf16x8 aXr[8];
    #pragma unroll
    for (int kb = 0; kb < 8; ++kb)
      aXr[kb] = *reinterpret_cast<const bf16x8*>(&pX[tokA * 256 + ((kb * 32 + lg * 8) ^ swA)]);
    // layer1 (swapped): C row = n1, col = token -> packed pH write
    #pragma unroll
    for (int nt1 = 0; nt1 < 4; ++nt1) {
      f32x4 c1 = {0.f, 0.f, 0.f, 0.f};
      #pragma unroll
      for (int kb = 0; kb < 8; ++kb) {
        bf16x8 bw = *reinterpret_cast<const bf16x8*>(&c1f[(nt1 * 8 + kb) * 512 + lane * 8]);
        c1 = __builtin_amdgcn_mfma_f32_16x16x32_bf16(bw, aXr[kb], c1, 0, 0, 0);
      }
      const float4 b14 = *reinterpret_cast<const float4*>(&ca_b1[nt1 * 16 + lg * 4]);
      uint2 pk;
      pk.x = f2b2(fmaxf(c1[0] + b14.x, 0.f), fmaxf(c1[1] + b14.y, 0.f));
      pk.y = f2b2(fmaxf(c1[2] + b14.z, 0.f), fmaxf(c1[3] + b14.w, 0.f));
      int d0 = nt1 * 16 + lg * 4;
      *reinterpret_cast<uint2*>(&pH[tokA * 64 + (d0 ^ swA)]) = pk;
    }
    bf16x8 hB[2];
    #pragma unroll
    for (int kb = 0; kb < 2; ++kb)
      hB[kb] = *reinterpret_cast<const bf16x8*>(&pH[tokA * 64 + ((kb * 32 + lg * 8) ^ swA)]);
    #pragma unroll
    for (int nt = 0; nt < 16; ++nt) {
      f32x4 a2 = {0.f, 0.f, 0.f, 0.f};
      #pragma unroll
      for (int kb = 0; kb < 2; ++kb) {
        bf16x8 w2a = *reinterpret_cast<const bf16x8*>(&c2f[(nt * 2 + kb) * 512 + lane * 8]);
        a2 = __builtin_amdgcn_mfma_f32_16x16x32_bf16(w2a, hB[kb], a2, 0, 0, 0);
      }
      const int n0 = nt * 16 + lg * 4;
      const float4 b24 = *reinterpret_cast<const float4*>(&ca_b2[n0]);
      const ushort4 xq = *reinterpret_cast<const ushort4*>(&pX[tokA * 256 + (n0 ^ swA)]);
      float xg0 = b2f(xq.x) / (1.f + __expf(-(a2[0] + b24.x)));
      float xg1 = b2f(xq.y) / (1.f + __expf(-(a2[1] + b24.y)));
      float xg2 = b2f(xq.z) / (1.f + __expf(-(a2[2] + b24.z)));
      float xg3 = b2f(xq.w) / (1.f + __expf(-(a2[3] + b24.w)));
      uint2 pk;
      pk.x = f2b2(xg0, xg1);
      pk.y = f2b2(xg2, xg3);
      gpk[nt] = pk;
      *reinterpret_cast<uint2*>(&pX[tokA * 256 + (n0 ^ swA)]) = pk;
    }
  }

  // ---- x2w init = bf16(xg + out_b) : 16 transposed uint2 NT stores ----
  {
    u16* wout = x2w + (size_t)wid * 16384;
    #pragma unroll
    for (int nt0 = 0; nt0 < 4; ++nt0) {
      #pragma unroll
      for (int r = 0; r < 4; ++r) {
        int cq = nt0 * 16 + lg * 4 + r;
        unsigned v0 = (r < 2) ? (gpk[nt0     ].x >> (16 * r)) : (gpk[nt0     ].y >> (16 * (r - 2)));
        unsigned v1 = (r < 2) ? (gpk[nt0 +  4].x >> (16 * r)) : (gpk[nt0 +  4].y >> (16 * (r - 2)));
        unsigned v2 = (r < 2) ? (gpk[nt0 +  8].x >> (16 * r)) : (gpk[nt0 +  8].y >> (16 * (r - 2)));
        unsigned v3 = (r < 2) ? (gpk[nt0 + 12].x >> (16 * r)) : (gpk[nt0 + 12].y >> (16 * (r - 2)));
        u32x2 o;
        o[0] = f2b2(b2f((u16)v0) + out_b[cq],       b2f((u16)v1) + out_b[cq + 64]);
        o[1] = f2b2(b2f((u16)v2) + out_b[cq + 128], b2f((u16)v3) + out_b[cq + 192]);
        __builtin_nontemporal_store(o, reinterpret_cast<u32x2*>(&wout[cq * 256 + tokA * 4]));
      }
    }
  }

  // ---- xg A-fragments for own strip (8 frags, reused all heads) ----
  bf16x8 aG[8];
  #pragma unroll
  for (int kb = 0; kb < 8; ++kb)
    aG[kb] = *reinterpret_cast<const bf16x8*>(&pX[tokA * 256 + ((kb * 32 + lg * 8) ^ swA)]);
  __syncthreads();   // pX dead; pQ/pK/pVT take over the same memory

  u16* ogw = Og + (size_t)wid * 16384;

  for (int h = 0; h < 4; ++h) {
    // ---------- QKV (swapped): C row = out-ch, col = token; packed Q/K writes ----------
    #pragma unroll 2
    for (int tau = 0; tau < 12; ++tau) {
      int kind = tau >> 2, sub = tau & 3;
      int colbase = kind * 256 + h * 64 + sub * 16;
      int T = kind * 16 + h * 4 + sub;
      f32x4 acc = {0.f, 0.f, 0.f, 0.f};
      #pragma unroll
      for (int kb = 0; kb < 8; ++kb) {
        bf16x8 bw = *reinterpret_cast<const bf16x8*>(&wq2[(T * 8 + kb) * 512 + lane * 8]);
        acc = __builtin_amdgcn_mfma_f32_16x16x32_bf16(bw, aG[kb], acc, 0, 0, 0);
      }
      const float4 bia4 = *reinterpret_cast<const float4*>(&qkv_b[colbase + lg * 4]);
      if (kind == 2) {
        #pragma unroll
        for (int r = 0; r < 4; ++r) {
          int d = sub * 16 + lg * 4 + r;
          float bv = (r == 0) ? bia4.x : (r == 1) ? bia4.y : (r == 2) ? bia4.z : bia4.w;
          pVT[d * 64 + (tokA ^ ((d & 7) << 3))] = f2b(acc[r] + bv);
        }
      } else {
        uint2 pk;
        pk.x = f2b2(acc[0] + bia4.x, acc[1] + bia4.y);
        pk.y = f2b2(acc[2] + bia4.z, acc[3] + bia4.w);
        int d0 = sub * 16 + lg * 4;
        u16* dst = (kind == 0) ? pQ : pK;
        *reinterpret_cast<uint2*>(&dst[tokA * 64 + (d0 ^ swA)]) = pk;
      }
    }
    __syncthreads();

    // ---------- scores S = Q @ K^T (strip rows) ----------
    bf16x8 aQ[2];
    #pragma unroll
    for (int kb = 0; kb < 2; ++kb)
      aQ[kb] = *reinterpret_cast<const bf16x8*>(&pQ[tokA * 64 + ((kb * 32 + lg * 8) ^ swA)]);
    f32x4 s4[4];
    #pragma unroll
    for (int jt = 0; jt < 4; ++jt) {
      int krow = jt * 16 + l15;
      int swk = SWZ8(krow);
      f32x4 acc = {0.f, 0.f, 0.f, 0.f};
      #pragma unroll
      for (int kb = 0; kb < 2; ++kb) {
        bf16x8 bK = *reinterpret_cast<const bf16x8*>(&pK[krow * 64 + ((kb * 32 + lg * 8) ^ swk)]);
        acc = __builtin_amdgcn_mfma_f32_16x16x32_bf16(aQ[kb], bK, acc, 0, 0, 0);
      }
      s4[jt] = acc;
    }
    // ---------- softmax per row, P overwrites own pQ strip ----------
    #pragma unroll
    for (int r = 0; r < 4; ++r) {
      float m = fmaxf(fmaxf(s4[0][r], s4[1][r]), fmaxf(s4[2][r], s4[3][r]));
      #pragma unroll
      for (int off = 1; off < 16; off <<= 1) m = fmaxf(m, __shfl_xor(m, off));
      float e0 = __expf((s4[0][r] - m) * 0.125f);
      float e1 = __expf((s4[1][r] - m) * 0.125f);
      float e2 = __expf((s4[2][r] - m) * 0.125f);
      float e3 = __expf((s4[3][r] - m) * 0.125f);
      float sum = e0 + e1 + e2 + e3;
      #pragma unroll
      for (int off = 1; off < 16; off <<= 1) sum += __shfl_xor(sum, off);
      float is = 1.f / sum;
      int tok = wv * 16 + lg * 4 + r;
      int swp = SWZ8(tok);
      pQ[tok * 64 + ((     l15) ^ swp)] = f2b(e0 * is);
      pQ[tok * 64 + ((16 + l15) ^ swp)] = f2b(e1 * is);
      pQ[tok * 64 + ((32 + l15) ^ swp)] = f2b(e2 * is);
      pQ[tok * 64 + ((48 + l15) ^ swp)] = f2b(e3 * is);
    }
    // ---------- PV: O^T = V^T @ P^T (strip-private) ----------
    bf16x8 bP[2];
    #pragma unroll
    for (int kb = 0; kb < 2; ++kb)
      bP[kb] = *reinterpret_cast<const bf16x8*>(&pQ[tokA * 64 + ((kb * 32 + lg * 8) ^ swA)]);
    #pragma unroll
    for (int dt = 0; dt < 4; ++dt) {
      int drow = dt * 16 + l15;
      int swd = (drow & 7) << 3;
      f32x4 acc = {0.f, 0.f, 0.f, 0.f};
      #pragma unroll
      for (int kb = 0; kb < 2; ++kb) {
        bf16x8 aV = *reinterpret_cast<const bf16x8*>(&pVT[drow * 64 + ((kb * 32 + lg * 8) ^ swd)]);
        acc = __builtin_amdgcn_mfma_f32_16x16x32_bf16(aV, bP[kb], acc, 0, 0, 0);
      }
      int d0 = h * 64 + dt * 16 + lg * 4;
      uint2 pk;
      pk.x = f2b2(acc[0], acc[1]);
      pk.y = f2b2(acc[2], acc[3]);
      *reinterpret_cast<uint2*>(&ogw[(d0 >> 2) * 256 + tokA * 4]) = pk;
    }
    __syncthreads();
  }
}

// ---------------- Kernel A2: out-proj GEMM, x2w += O @ Wout (bf16 RMW) ----------------
__global__ __launch_bounds__(256, 3) void kb_oproj(
    const u16* __restrict__ Og, const u16* __restrict__ wo2,
    u16* __restrict__ x2w)
{
  const int tid = threadIdx.x;
  const int lane = tid & 63;
  const int wv = __builtin_amdgcn_readfirstlane(tid >> 6);
  const int l15 = lane & 15;
  const int lg = lane >> 4;
  const int bid = blockIdx.x;
  const int wid = (bid & 7) * 256 + (bid >> 3);   // XCD-chunked (matches kb_attn)
  const int tokA = wv * 16 + l15;

  const u16* og = Og + (size_t)wid * 16384;
  bf16x8 bO[8];
  #pragma unroll
  for (int kb = 0; kb < 8; ++kb) {
    int dq = kb * 8 + lg * 2;
    uint2 lo = *reinterpret_cast<const uint2*>(&og[dq * 256 + tokA * 4]);
    uint2 hi = *reinterpret_cast<const uint2*>(&og[(dq + 1) * 256 + tokA * 4]);
    union { uint4 u; bf16x8 v; } cvt;
    cvt.u.x = lo.x; cvt.u.y = lo.y; cvt.u.z = hi.x; cvt.u.w = hi.y;
    bO[kb] = cvt.v;
  }

  f32x4 acc[16];
  #pragma unroll
  for (int nt = 0; nt < 16; ++nt) {
    f32x4 z = {0.f, 0.f, 0.f, 0.f};
    acc[nt] = z;
  }
  #pragma unroll
  for (int nt = 0; nt < 16; ++nt) {
    #pragma unroll
    for (int kb = 0; kb < 8; ++kb) {
      bf16x8 wA = *reinterpret_cast<const bf16x8*>(&wo2[(nt * 8 + kb) * 512 + lane * 8]);
      acc[nt] = __builtin_amdgcn_mfma_f32_16x16x32_bf16(wA, bO[kb], acc[nt], 0, 0, 0);
    }
  }

  u16* wout = x2w + (size_t)wid * 16384;
  #pragma unroll
  for (int nt0 = 0; nt0 < 4; ++nt0) {
    #pragma unroll
    for (int r = 0; r < 4; ++r) {
      int cq = nt0 * 16 + lg * 4 + r;
      u16* p = &wout[cq * 256 + tokA * 4];
      uint2 cur = *reinterpret_cast<const uint2*>(p);
      float c0 = b2f((u16)(cur.x & 0xffff)) + acc[nt0     ][r];
      float c1 = b2f((u16)(cur.x >> 16))    + acc[nt0 +  4][r];
      float c2 = b2f((u16)(cur.y & 0xffff)) + acc[nt0 +  8][r];
      float c3 = b2f((u16)(cur.y >> 16))    + acc[nt0 + 12][r];
      uint2 o;
      o.x = f2b2(c0, c1);
      o.y = f2b2(c2, c3);
      *reinterpret_cast<uint2*>(p) = o;
    }
  }
}

// ---------------- Kernel C: grouped conv1 + BN + ReLU (bf16 in, bf16 out) ----------------
__global__ __launch_bounds__(256) void kc_conv1(
    const u16* __restrict__ x2w, const float* __restrict__ w1, const float* __restrict__ b1,
    const float* __restrict__ g1, const float* __restrict__ bb1,
    const float* __restrict__ m1, const float* __restrict__ v1,
    u16* __restrict__ y1)
{
  __shared__ float sin_[4 * 22 * 72];
  const int bid = blockIdx.x;
  const int wid = (bid & 7) * 1024 + (bid >> 3);     // XCD-chunked
  int b = wid >> 8, rem = wid & 255, j = rem >> 2, qt = rem & 3;
  const u16* xw = x2w + (size_t)b * 64 * 16384;
  for (int idx = threadIdx.x; idx < 22 * 70; idx += 256) {
    int yy = idx / 70, xx = idx - yy * 70;
    int ih = qt * 16 + yy - 3, iw = xx - 3;
    uint2 v = {0u, 0u};
    if (ih >= 0 && ih < 64 && iw >= 0 && iw < 64) {
      int wr = (ih >> 3) * 8 + (iw >> 3);
      int tok = (ih & 7) * 8 + (iw & 7);
      v = *reinterpret_cast<const uint2*>(&xw[(size_t)wr * 16384 + j * 256 + tok * 4]);
    }
    sin_[0 * 1584 + yy * 72 + xx] = b2f((u16)(v.x & 0xffff));
    sin_[1 * 1584 + yy * 72 + xx] = b2f((u16)(v.x >> 16));
    sin_[2 * 1584 + yy * 72 + xx] = b2f((u16)(v.y & 0xffff));
    sin_[3 * 1584 + yy * 72 + xx] = b2f((u16)(v.y >> 16));
  }
  __syncthreads();

  float inv = g1[j] / sqrtf(v1[j] + 1e-5f);
  float shf = bb1[j] - m1[j] * inv;
  float bia = b1[j];
  u16* yo = y1 + ((size_t)b * 64 + j) * HW + qt * 16 * 64;
  const float* wbase = w1 + j * 4 * 49;

  int y = threadIdx.x >> 4, x4 = (threadIdx.x & 15) * 4;
  float a0 = 0.f, a1 = 0.f, a2 = 0.f, a3 = 0.f;
  for (int i = 0; i < 4; ++i) {
    #pragma unroll
    for (int ky = 0; ky < 7; ++ky) {
      const float* row = sin_ + (i * 22 + y + ky) * 72 + x4;
      const f32x4 p0 = *reinterpret_cast<const f32x4*>(row);
      const f32x4 p1 = *reinterpret_cast<const f32x4*>(row + 4);
      const f32x2 p2 = *reinterpret_cast<const f32x2*>(row + 8);
      float v[10] = {p0[0], p0[1], p0[2], p0[3], p1[0], p1[1], p1[2], p1[3], p2[0], p2[1]};
      const float* wr = wbase + (i * 7 + ky) * 7;
      #pragma unroll
      for (int kx = 0; kx < 7; ++kx) {
        float wvv = wr[kx];
        a0 += v[kx] * wvv; a1 += v[kx+1] * wvv;
        a2 += v[kx+2] * wvv; a3 += v[kx+3] * wvv;
      }
    }
  }
  u32x2 o;
  o[0] = f2b2(fmaxf((a0 + bia) * inv + shf, 0.f), fmaxf((a1 + bia) * inv + shf, 0.f));
  o[1] = f2b2(fmaxf((a2 + bia) * inv + shf, 0.f), fmaxf((a3 + bia) * inv + shf, 0.f));
  __builtin_nontemporal_store(o, reinterpret_cast<u32x2*>(yo + y * 64 + x4));
}

// ---------------- Kernel D: grouped conv2 + BN + sigmoid gate * x2w (bf16) ----------------
__global__ __launch_bounds__(256) void kd_conv2(
    const u16* __restrict__ y1, const u16* __restrict__ x2w,
    const float* __restrict__ w2, const float* __restrict__ b2,
    const float* __restrict__ g2, const float* __restrict__ bb2,
    const float* __restrict__ m2, const float* __restrict__ v2,
    float* __restrict__ out)
{
  __shared__ float sin_[70 * 72];
  const int bid = blockIdx.x;
  const int wid = (bid & 7) * 256 + (bid >> 3);      // XCD-chunked
  int b = wid >> 6, g = wid & 63;
  const u16* yin = y1 + ((size_t)b * 64 + g) * HW;

  // zero halo: rows 0-2 & 67-69 (full), cols {0,1,2,67,68,69} of rows 3..66
  for (int idx = threadIdx.x; idx < 6 * 72; idx += 256) {
    int r = idx / 72, c = idx - r * 72;
    sin_[(r < 3 ? r : 64 + r) * 72 + c] = 0.f;
  }
  for (int idx = threadIdx.x; idx < 64 * 6; idx += 256) {
    int r = idx / 6, c = idx - r * 6;
    sin_[(r + 3) * 72 + (c < 3 ? c : 64 + c)] = 0.f;
  }
  // interior: uint2 global loads (4 bf16), scalar LDS writes
  for (int idx = threadIdx.x; idx < 64 * 16; idx += 256) {
    int r = idx >> 4, c4 = (idx & 15) * 4;
    uint2 v = *reinterpret_cast<const uint2*>(&yin[r * 64 + c4]);
    float* d = &sin_[(r + 3) * 72 + 3 + c4];
    d[0] = b2f((u16)(v.x & 0xffff)); d[1] = b2f((u16)(v.x >> 16));
    d[2] = b2f((u16)(v.y & 0xffff)); d[3] = b2f((u16)(v.y >> 16));
  }
  __syncthreads();

  float inv[4], shf[4], bia[4];
  #pragma unroll
  for (int i = 0; i < 4; ++i) {
    int n = 4 * g + i;
    float sc = g2[n] / sqrtf(v2[n] + 1e-5f);
    inv[i] = sc; shf[i] = bb2[n] - m2[n] * sc; bia[i] = b2[n];
  }
  const float* wb = w2 + 4 * g * 49;
  const u16* xw = x2w + (size_t)b * 64 * 16384;

  for (int it = 0; it < 4; ++it) {
    int s = it * 256 + threadIdx.x;
    int y = s >> 4, x4 = (s & 15) * 4;
    float acc[4][4] = {};
    #pragma unroll
    for (int ky = 0; ky < 7; ++ky) {
      const float* row = sin_ + (y + ky) * 72 + x4;
      const f32x4 p0 = *reinterpret_cast<const f32x4*>(row);
      const f32x4 p1 = *reinterpret_cast<const f32x4*>(row + 4);
      const f32x2 p2 = *reinterpret_cast<const f32x2*>(row + 8);
      float v[10] = {p0[0], p0[1], p0[2], p0[3], p1[0], p1[1], p1[2], p1[3], p2[0], p2[1]};
      #pragma unroll
      for (int i = 0; i < 4; ++i) {
        const float* wr = wb + i * 49 + ky * 7;
        #pragma unroll
        for (int kx = 0; kx < 7; ++kx) {
          float wvv = wr[kx];
          acc[i][0] += v[kx] * wvv; acc[i][1] += v[kx+1] * wvv;
          acc[i][2] += v[kx+2] * wvv; acc[i][3] += v[kx+3] * wvv;
        }
      }
    }
    int po = y * 64 + x4;
    int wr_ = (y >> 3) * 8 + (x4 >> 3);
    int t0 = (y & 7) * 8 + (x4 & 7);
    const u16* gp = &xw[(size_t)wr_ * 16384 + g * 256 + t0 * 4];
    uint2 q0 = *reinterpret_cast<const uint2*>(gp + 0);
    uint2 q1 = *reinterpret_cast<const uint2*>(gp + 4);
    uint2 q2 = *reinterpret_cast<const uint2*>(gp + 8);
    uint2 q3 = *reinterpret_cast<const uint2*>(gp + 12);
    #pragma unroll
    for (int i = 0; i < 4; ++i) {
      int n = 4 * g + i;
      float* op = out + ((size_t)b * 256 + n) * HW + po;
      float y0 = (acc[i][0] + bia[i]) * inv[i] + shf[i];
      float y1v = (acc[i][1] + bia[i]) * inv[i] + shf[i];
      float y2 = (acc[i][2] + bia[i]) * inv[i] + shf[i];
      float y3 = (acc[i][3] + bia[i]) * inv[i] + shf[i];
      float g0 = b2f((u16)(i < 2 ? (q0.x >> (16 * i)) : (q0.y >> (16 * (i - 2)))));
      float g1v = b2f((u16)(i < 2 ? (q1.x >> (16 * i)) : (q1.y >> (16 * (i - 2)))));
      float g2v = b2f((u16)(i < 2 ? (q2.x >> (16 * i)) : (q2.y >> (16 * (i - 2)))));
      float g3 = b2f((u16)(i < 2 ? (q3.x >> (16 * i)) : (q3.y >> (16 * (i - 2)))));
      float4 r;
      r.x = g0  / (1.f + __expf(-y0));
      r.y = g1v / (1.f + __expf(-y1v));
      r.z = g2v / (1.f + __expf(-y2));
      r.w = g3  / (1.f + __expf(-y3));
      nt_store4(r, op);
    }
  }
}

extern "C" void kernel_launch(void* const* d_in, const int* in_sizes, int n_in,
                              void* d_out, int out_size, void* d_ws, size_t ws_size,
                              hipStream_t stream) {
  const float* x     = (const float*)d_in[0];
  const float* qkv_w = (const float*)d_in[1];
  const float* qkv_b = (const float*)d_in[2];
  const float* out_w = (const float*)d_in[3];
  const float* out_b = (const float*)d_in[4];
  const float* ca_w1 = (const float*)d_in[5];
  const float* ca_b1 = (const float*)d_in[6];
  const float* ca_w2 = (const float*)d_in[7];
  const float* ca_b2 = (const float*)d_in[8];
  const float* sa_w1 = (const float*)d_in[9];
  const float* sa_b1 = (const float*)d_in[10];
  const float* bn1_g = (const float*)d_in[11];
  const float* bn1_b = (const float*)d_in[12];
  const float* bn1_m = (const float*)d_in[13];
  const float* bn1_v = (const float*)d_in[14];
  const float* sa_w2 = (const float*)d_in[15];
  const float* sa_b2 = (const float*)d_in[16];
  const float* bn2_g = (const float*)d_in[17];
  const float* bn2_b = (const float*)d_in[18];
  const float* bn2_m = (const float*)d_in[19];
  const float* bn2_v = (const float*)d_in[20];

  float* outp = (float*)d_out;
  u16* x2w = (u16*)d_ws;                            // [win][cq][tok][quad] bf16, 64 MB
  u16* y1 = x2w + (size_t)2048 * 16384;             // conv1 output bf16, 16 MB

  // bf16 weights + O buffer stashed in d_out (overwritten by kd at the end)
  u16* wq2 = (u16*)d_out;                           // 196608
  u16* wo2 = wq2 + 48 * 8 * 512;                    // 65536
  u16* c1f = wo2 + 16 * 8 * 512;                    // 16384
  u16* c2f = c1f + 4 * 8 * 512;                     // 16384
  u16* Og  = c2f + 16 * 2 * 512;                    // 2048*16384 u16 = 64 MB

  kprep   <<<768,  256, 0, stream>>>(qkv_w, out_w, ca_w1, ca_w2, wq2, wo2, c1f, c2f);
  kb_attn <<<2048, 256, 0, stream>>>(x, x2w, Og, wq2, qkv_b, out_b, c1f, ca_b1, c2f, ca_b2);
  kb_oproj<<<2048, 256, 0, stream>>>(Og, wo2, x2w);
  kc_conv1<<<8192, 256, 0, stream>>>(x2w, sa_w1, sa_b1, bn1_g, bn1_b, bn1_m, bn1_v, y1);
  kd_conv2<<<2048, 256, 0, stream>>>(y1, x2w, sa_w2, sa_b2, bn2_g, bn2_b, bn2_m, bn2_v, outp);
}

// Round 23
// 411.240 us; speedup vs baseline: 1.4453x; 1.0178x over previous
//
#include <hip/hip_runtime.h>

#define HW 4096
#define CCH 256

typedef __bf16 bf16x8 __attribute__((ext_vector_type(8)));
typedef float f32x4 __attribute__((ext_vector_type(4)));
typedef float f32x2 __attribute__((ext_vector_type(2)));
typedef unsigned u32x2 __attribute__((ext_vector_type(2)));
typedef unsigned short u16;

// LDS row swizzle: spreads 8 ways even when rows step by 4
#define SWZ8(r) ((((r) + ((r) >> 2)) & 7) << 3)

__device__ __forceinline__ u16 f2b(float f) {
  union { __bf16 h; u16 u; } c; c.h = (__bf16)f; return c.u;   // v_cvt (RNE)
}
__device__ __forceinline__ unsigned f2b2(float a, float b) {
  union { __bf16 h[2]; unsigned u; } c;                        // v_cvt_pk_bf16_f32
  c.h[0] = (__bf16)a; c.h[1] = (__bf16)b; return c.u;
}
__device__ __forceinline__ float b2f(u16 h) {
  union { unsigned u; float f; } v; v.u = ((unsigned)h) << 16; return v.f;
}
__device__ __forceinline__ void nt_store4(const float4& v, float* p) {
  f32x4 t; t[0] = v.x; t[1] = v.y; t[2] = v.z; t[3] = v.w;
  __builtin_nontemporal_store(t, reinterpret_cast<f32x4*>(p));
}

// ---------------- Kernel P: fragment-major bf16 weight relayouts ----------------
__global__ __launch_bounds__(256) void kprep(
    const float* __restrict__ qkv_w, const float* __restrict__ out_w,
    const float* __restrict__ ca_w1, const float* __restrict__ ca_w2,
    u16* __restrict__ wq2, u16* __restrict__ wo2,
    u16* __restrict__ c1f, u16* __restrict__ c2f)
{
  int i = blockIdx.x * 256 + threadIdx.x;
  int j = i & 7, lane = (i >> 3) & 63, l15 = lane & 15, lg = lane >> 4;
  if (i < 48 * 8 * 512) {                      // qkv: 48 n-tiles, K=256 (8 kb)
    int kb = (i >> 9) & 7, T = i >> 12;
    wq2[i] = f2b(qkv_w[(kb * 32 + lg * 8 + j) * 768 + T * 16 + l15]);
  }
  if (i < 16 * 8 * 512) {                      // out: 16 n-tiles, K=256
    int kb = (i >> 9) & 7, T = i >> 12;
    wo2[i] = f2b(out_w[(kb * 32 + lg * 8 + j) * 256 + T * 16 + l15]);
  }
  if (i < 4 * 8 * 512) {                       // ca_w1: 4 n-tiles (n<64), K=256
    int kb = (i >> 9) & 7, T = i >> 12;
    c1f[i] = f2b(ca_w1[(kb * 32 + lg * 8 + j) * 64 + T * 16 + l15]);
  }
  if (i < 16 * 2 * 512) {                      // ca_w2: 16 n-tiles, K=64 (2 kb)
    int kb = (i >> 9) & 1, T = i >> 10;
    c2f[i] = f2b(ca_w2[(kb * 32 + lg * 8 + j) * 256 + T * 16 + l15]);
  }
}

// ---------------- Kernel A: CA-gate + windowed MHSA (O to global) ----------------
// Swapped-operand MFMA epilogues: C = (row=out-ch, col=token) -> packed uint2
// LDS writes (consecutive d in the lane's own token row).
__global__ __launch_bounds__(256, 4) void kb_attn(
    const float* __restrict__ x, u16* __restrict__ x2w, u16* __restrict__ Og,
    const u16* __restrict__ wq2, const float* __restrict__ qkv_b,
    const float* __restrict__ out_b,
    const u16* __restrict__ c1f, const float* __restrict__ ca_b1,
    const u16* __restrict__ c2f, const float* __restrict__ ca_b2)
{
  __shared__ u16 smem[20480];          // 40 KB
  u16* pX  = smem;                     // [64][256] x -> xg      (32 KB, phase 1)
  u16* pH  = smem + 16384;             // [64][64] hidden H      ( 8 KB, phase 1)
  u16* pQ  = smem;                     // [64][64] Q -> P        (phase 2, aliases pX)
  u16* pK  = smem + 4096;              // [64][64] K
  u16* pVT = smem + 8192;              // [64][64] V^T

  const int tid = threadIdx.x;
  const int lane = tid & 63;
  const int wv = __builtin_amdgcn_readfirstlane(tid >> 6);
  const int l15 = lane & 15;
  const int lg = lane >> 4;

  const int bid = blockIdx.x;
  const int wid = (bid & 7) * 256 + (bid >> 3);   // XCD-chunked
  const int b = wid >> 6, wrem = wid & 63;
  const int pbase = (wrem >> 3) * (8 * 64) + (wrem & 7) * 8;
  const float* ximg = x + (size_t)b * CCH * HW;

  const int tokA = wv * 16 + l15;          // wave strip row
  const int swA = SWZ8(tokA);

  // ---- stage raw x -> pX via float4 ----
  {
    const int t0 = l15 * 4;
    const int prow = pbase + (l15 >> 1) * 64 + (l15 & 1) * 4;
    #pragma unroll 2
    for (int i = 0; i < 16; ++i) {
      int c = i * 16 + wv * 4 + lg;
      const float4 v = *reinterpret_cast<const float4*>(&ximg[(size_t)c * HW + prow]);
      pX[(t0 + 0) * 256 + (c ^ SWZ8(t0 + 0))] = f2b(v.x);
      pX[(t0 + 1) * 256 + (c ^ SWZ8(t0 + 1))] = f2b(v.y);
      pX[(t0 + 2) * 256 + (c ^ SWZ8(t0 + 2))] = f2b(v.z);
      pX[(t0 + 3) * 256 + (c ^ SWZ8(t0 + 3))] = f2b(v.w);
    }
  }
  __syncthreads();

  // ---- channel-attention gating; xg overwrites x in pX; gate kept in regs ----
  uint2 gpk[16];                       // bf16-pair gate values per n-tile (32 VGPR)
  {
    bf16x8 aXr[8];
    #pragma unroll
    for (int kb = 0; kb < 8; ++kb)
      aXr[kb] = *reinterpret_cast<const bf16x8*>(&pX[tokA * 256 + ((kb * 32 + lg * 8) ^ swA)]);
    // layer1 (swapped): C row = n1, col = token -> packed pH write
    #pragma unroll
    for (int nt1 = 0; nt1 < 4; ++nt1) {
      f32x4 c1 = {0.f, 0.f, 0.f, 0.f};
      #pragma unroll
      for (int kb = 0; kb < 8; ++kb) {
        bf16x8 bw = *reinterpret_cast<const bf16x8*>(&c1f[(nt1 * 8 + kb) * 512 + lane * 8]);
        c1 = __builtin_amdgcn_mfma_f32_16x16x32_bf16(bw, aXr[kb], c1, 0, 0, 0);
      }
      const float4 b14 = *reinterpret_cast<const float4*>(&ca_b1[nt1 * 16 + lg * 4]);
      uint2 pk;
      pk.x = f2b2(fmaxf(c1[0] + b14.x, 0.f), fmaxf(c1[1] + b14.y, 0.f));
      pk.y = f2b2(fmaxf(c1[2] + b14.z, 0.f), fmaxf(c1[3] + b14.w, 0.f));
      int d0 = nt1 * 16 + lg * 4;
      *reinterpret_cast<uint2*>(&pH[tokA * 64 + (d0 ^ swA)]) = pk;
    }
    bf16x8 hB[2];
    #pragma unroll
    for (int kb = 0; kb < 2; ++kb)
      hB[kb] = *reinterpret_cast<const bf16x8*>(&pH[tokA * 64 + ((kb * 32 + lg * 8) ^ swA)]);
    #pragma unroll
    for (int nt = 0; nt < 16; ++nt) {
      f32x4 a2 = {0.f, 0.f, 0.f, 0.f};
      #pragma unroll
      for (int kb = 0; kb < 2; ++kb) {
        bf16x8 w2a = *reinterpret_cast<const bf16x8*>(&c2f[(nt * 2 + kb) * 512 + lane * 8]);
        a2 = __builtin_amdgcn_mfma_f32_16x16x32_bf16(w2a, hB[kb], a2, 0, 0, 0);
      }
      const int n0 = nt * 16 + lg * 4;
      const float4 b24 = *reinterpret_cast<const float4*>(&ca_b2[n0]);
      const ushort4 xq = *reinterpret_cast<const ushort4*>(&pX[tokA * 256 + (n0 ^ swA)]);
      float xg0 = b2f(xq.x) / (1.f + __expf(-(a2[0] + b24.x)));
      float xg1 = b2f(xq.y) / (1.f + __expf(-(a2[1] + b24.y)));
      float xg2 = b2f(xq.z) / (1.f + __expf(-(a2[2] + b24.z)));
      float xg3 = b2f(xq.w) / (1.f + __expf(-(a2[3] + b24.w)));
      uint2 pk;
      pk.x = f2b2(xg0, xg1);
      pk.y = f2b2(xg2, xg3);
      gpk[nt] = pk;
      *reinterpret_cast<uint2*>(&pX[tokA * 256 + (n0 ^ swA)]) = pk;
    }
  }

  // ---- x2w init = bf16(xg + out_b) : 16 transposed uint2 NT stores ----
  {
    u16* wout = x2w + (size_t)wid * 16384;
    #pragma unroll
    for (int nt0 = 0; nt0 < 4; ++nt0) {
      #pragma unroll
      for (int r = 0; r < 4; ++r) {
        int cq = nt0 * 16 + lg * 4 + r;
        unsigned v0 = (r < 2) ? (gpk[nt0     ].x >> (16 * r)) : (gpk[nt0     ].y >> (16 * (r - 2)));
        unsigned v1 = (r < 2) ? (gpk[nt0 +  4].x >> (16 * r)) : (gpk[nt0 +  4].y >> (16 * (r - 2)));
        unsigned v2 = (r < 2) ? (gpk[nt0 +  8].x >> (16 * r)) : (gpk[nt0 +  8].y >> (16 * (r - 2)));
        unsigned v3 = (r < 2) ? (gpk[nt0 + 12].x >> (16 * r)) : (gpk[nt0 + 12].y >> (16 * (r - 2)));
        u32x2 o;
        o[0] = f2b2(b2f((u16)v0) + out_b[cq],       b2f((u16)v1) + out_b[cq + 64]);
        o[1] = f2b2(b2f((u16)v2) + out_b[cq + 128], b2f((u16)v3) + out_b[cq + 192]);
        __builtin_nontemporal_store(o, reinterpret_cast<u32x2*>(&wout[cq * 256 + tokA * 4]));
      }
    }
  }

  // ---- xg A-fragments for own strip (8 frags, reused all heads) ----
  bf16x8 aG[8];
  #pragma unroll
  for (int kb = 0; kb < 8; ++kb)
    aG[kb] = *reinterpret_cast<const bf16x8*>(&pX[tokA * 256 + ((kb * 32 + lg * 8) ^ swA)]);
  __syncthreads();   // pX dead; pQ/pK/pVT take over the same memory

  u16* ogw = Og + (size_t)wid * 16384;

  for (int h = 0; h < 4; ++h) {
    // ---------- QKV (swapped): C row = out-ch, col = token; packed Q/K writes ----------
    #pragma unroll 2
    for (int tau = 0; tau < 12; ++tau) {
      int kind = tau >> 2, sub = tau & 3;
      int colbase = kind * 256 + h * 64 + sub * 16;
      int T = kind * 16 + h * 4 + sub;
      f32x4 acc = {0.f, 0.f, 0.f, 0.f};
      #pragma unroll
      for (int kb = 0; kb < 8; ++kb) {
        bf16x8 bw = *reinterpret_cast<const bf16x8*>(&wq2[(T * 8 + kb) * 512 + lane * 8]);
        acc = __builtin_amdgcn_mfma_f32_16x16x32_bf16(bw, aG[kb], acc, 0, 0, 0);
      }
      const float4 bia4 = *reinterpret_cast<const float4*>(&qkv_b[colbase + lg * 4]);
      if (kind == 2) {
        #pragma unroll
        for (int r = 0; r < 4; ++r) {
          int d = sub * 16 + lg * 4 + r;
          float bv = (r == 0) ? bia4.x : (r == 1) ? bia4.y : (r == 2) ? bia4.z : bia4.w;
          pVT[d * 64 + (tokA ^ ((d & 7) << 3))] = f2b(acc[r] + bv);
        }
      } else {
        uint2 pk;
        pk.x = f2b2(acc[0] + bia4.x, acc[1] + bia4.y);
        pk.y = f2b2(acc[2] + bia4.z, acc[3] + bia4.w);
        int d0 = sub * 16 + lg * 4;
        u16* dst = (kind == 0) ? pQ : pK;
        *reinterpret_cast<uint2*>(&dst[tokA * 64 + (d0 ^ swA)]) = pk;
      }
    }
    __syncthreads();

    // ---------- scores S = Q @ K^T (strip rows) ----------
    bf16x8 aQ[2];
    #pragma unroll
    for (int kb = 0; kb < 2; ++kb)
      aQ[kb] = *reinterpret_cast<const bf16x8*>(&pQ[tokA * 64 + ((kb * 32 + lg * 8) ^ swA)]);
    f32x4 s4[4];
    #pragma unroll
    for (int jt = 0; jt < 4; ++jt) {
      int krow = jt * 16 + l15;
      int swk = SWZ8(krow);
      f32x4 acc = {0.f, 0.f, 0.f, 0.f};
      #pragma unroll
      for (int kb = 0; kb < 2; ++kb) {
        bf16x8 bK = *reinterpret_cast<const bf16x8*>(&pK[krow * 64 + ((kb * 32 + lg * 8) ^ swk)]);
        acc = __builtin_amdgcn_mfma_f32_16x16x32_bf16(aQ[kb], bK, acc, 0, 0, 0);
      }
      s4[jt] = acc;
    }
    // ---------- softmax per row, P overwrites own pQ strip ----------
    #pragma unroll
    for (int r = 0; r < 4; ++r) {
      float m = fmaxf(fmaxf(s4[0][r], s4[1][r]), fmaxf(s4[2][r], s4[3][r]));
      #pragma unroll
      for (int off = 1; off < 16; off <<= 1) m = fmaxf(m, __shfl_xor(m, off));
      float e0 = __expf((s4[0][r] - m) * 0.125f);
      float e1 = __expf((s4[1][r] - m) * 0.125f);
      float e2 = __expf((s4[2][r] - m) * 0.125f);
      float e3 = __expf((s4[3][r] - m) * 0.125f);
      float sum = e0 + e1 + e2 + e3;
      #pragma unroll
      for (int off = 1; off < 16; off <<= 1) sum += __shfl_xor(sum, off);
      float is = 1.f / sum;
      int tok = wv * 16 + lg * 4 + r;
      int swp = SWZ8(tok);
      pQ[tok * 64 + ((     l15) ^ swp)] = f2b(e0 * is);
      pQ[tok * 64 + ((16 + l15) ^ swp)] = f2b(e1 * is);
      pQ[tok * 64 + ((32 + l15) ^ swp)] = f2b(e2 * is);
      pQ[tok * 64 + ((48 + l15) ^ swp)] = f2b(e3 * is);
    }
    // ---------- PV: O^T = V^T @ P^T (strip-private) ----------
    bf16x8 bP[2];
    #pragma unroll
    for (int kb = 0; kb < 2; ++kb)
      bP[kb] = *reinterpret_cast<const bf16x8*>(&pQ[tokA * 64 + ((kb * 32 + lg * 8) ^ swA)]);
    #pragma unroll
    for (int dt = 0; dt < 4; ++dt) {
      int drow = dt * 16 + l15;
      int swd = (drow & 7) << 3;
      f32x4 acc = {0.f, 0.f, 0.f, 0.f};
      #pragma unroll
      for (int kb = 0; kb < 2; ++kb) {
        bf16x8 aV = *reinterpret_cast<const bf16x8*>(&pVT[drow * 64 + ((kb * 32 + lg * 8) ^ swd)]);
        acc = __builtin_amdgcn_mfma_f32_16x16x32_bf16(aV, bP[kb], acc, 0, 0, 0);
      }
      int d0 = h * 64 + dt * 16 + lg * 4;
      uint2 pk;
      pk.x = f2b2(acc[0], acc[1]);
      pk.y = f2b2(acc[2], acc[3]);
      *reinterpret_cast<uint2*>(&ogw[(d0 >> 2) * 256 + tokA * 4]) = pk;
    }
    __syncthreads();
  }
}

// ---------------- Kernel A2: out-proj GEMM, x2w += O @ Wout (bf16 RMW) ----------------
// 4 blocks/CU (live set ~112 VGPR fits 128); Og loads non-temporal (read-once).
__global__ __launch_bounds__(256, 4) void kb_oproj(
    const u16* __restrict__ Og, const u16* __restrict__ wo2,
    u16* __restrict__ x2w)
{
  const int tid = threadIdx.x;
  const int lane = tid & 63;
  const int wv = __builtin_amdgcn_readfirstlane(tid >> 6);
  const int l15 = lane & 15;
  const int lg = lane >> 4;
  const int bid = blockIdx.x;
  const int wid = (bid & 7) * 256 + (bid >> 3);   // XCD-chunked (matches kb_attn)
  const int tokA = wv * 16 + l15;

  const u16* og = Og + (size_t)wid * 16384;
  bf16x8 bO[8];
  #pragma unroll
  for (int kb = 0; kb < 8; ++kb) {
    int dq = kb * 8 + lg * 2;
    u32x2 lo = __builtin_nontemporal_load(reinterpret_cast<const u32x2*>(&og[dq * 256 + tokA * 4]));
    u32x2 hi = __builtin_nontemporal_load(reinterpret_cast<const u32x2*>(&og[(dq + 1) * 256 + tokA * 4]));
    union { unsigned u[4]; bf16x8 v; } cvt;
    cvt.u[0] = lo[0]; cvt.u[1] = lo[1]; cvt.u[2] = hi[0]; cvt.u[3] = hi[1];
    bO[kb] = cvt.v;
  }

  f32x4 acc[16];
  #pragma unroll
  for (int nt = 0; nt < 16; ++nt) {
    f32x4 z = {0.f, 0.f, 0.f, 0.f};
    acc[nt] = z;
  }
  #pragma unroll
  for (int nt = 0; nt < 16; ++nt) {
    #pragma unroll
    for (int kb = 0; kb < 8; ++kb) {
      bf16x8 wA = *reinterpret_cast<const bf16x8*>(&wo2[(nt * 8 + kb) * 512 + lane * 8]);
      acc[nt] = __builtin_amdgcn_mfma_f32_16x16x32_bf16(wA, bO[kb], acc[nt], 0, 0, 0);
    }
  }

  u16* wout = x2w + (size_t)wid * 16384;
  #pragma unroll
  for (int nt0 = 0; nt0 < 4; ++nt0) {
    #pragma unroll
    for (int r = 0; r < 4; ++r) {
      int cq = nt0 * 16 + lg * 4 + r;
      u16* p = &wout[cq * 256 + tokA * 4];
      uint2 cur = *reinterpret_cast<const uint2*>(p);
      float c0 = b2f((u16)(cur.x & 0xffff)) + acc[nt0     ][r];
      float c1 = b2f((u16)(cur.x >> 16))    + acc[nt0 +  4][r];
      float c2 = b2f((u16)(cur.y & 0xffff)) + acc[nt0 +  8][r];
      float c3 = b2f((u16)(cur.y >> 16))    + acc[nt0 + 12][r];
      uint2 o;
      o.x = f2b2(c0, c1);
      o.y = f2b2(c2, c3);
      *reinterpret_cast<uint2*>(p) = o;
    }
  }
}

// ---------------- Kernel C: grouped conv1 + BN + ReLU (bf16 in, bf16 out) ----------------
__global__ __launch_bounds__(256) void kc_conv1(
    const u16* __restrict__ x2w, const float* __restrict__ w1, const float* __restrict__ b1,
    const float* __restrict__ g1, const float* __restrict__ bb1,
    const float* __restrict__ m1, const float* __restrict__ v1,
    u16* __restrict__ y1)
{
  __shared__ float sin_[4 * 22 * 72];
  const int bid = blockIdx.x;
  const int wid = (bid & 7) * 1024 + (bid >> 3);     // XCD-chunked
  int b = wid >> 8, rem = wid & 255, j = rem >> 2, qt = rem & 3;
  const u16* xw = x2w + (size_t)b * 64 * 16384;
  for (int idx = threadIdx.x; idx < 22 * 70; idx += 256) {
    int yy = idx / 70, xx = idx - yy * 70;
    int ih = qt * 16 + yy - 3, iw = xx - 3;
    uint2 v = {0u, 0u};
    if (ih >= 0 && ih < 64 && iw >= 0 && iw < 64) {
      int wr = (ih >> 3) * 8 + (iw >> 3);
      int tok = (ih & 7) * 8 + (iw & 7);
      v = *reinterpret_cast<const uint2*>(&xw[(size_t)wr * 16384 + j * 256 + tok * 4]);
    }
    sin_[0 * 1584 + yy * 72 + xx] = b2f((u16)(v.x & 0xffff));
    sin_[1 * 1584 + yy * 72 + xx] = b2f((u16)(v.x >> 16));
    sin_[2 * 1584 + yy * 72 + xx] = b2f((u16)(v.y & 0xffff));
    sin_[3 * 1584 + yy * 72 + xx] = b2f((u16)(v.y >> 16));
  }
  __syncthreads();

  float inv = g1[j] / sqrtf(v1[j] + 1e-5f);
  float shf = bb1[j] - m1[j] * inv;
  float bia = b1[j];
  u16* yo = y1 + ((size_t)b * 64 + j) * HW + qt * 16 * 64;
  const float* wbase = w1 + j * 4 * 49;

  int y = threadIdx.x >> 4, x4 = (threadIdx.x & 15) * 4;
  float a0 = 0.f, a1 = 0.f, a2 = 0.f, a3 = 0.f;
  for (int i = 0; i < 4; ++i) {
    #pragma unroll
    for (int ky = 0; ky < 7; ++ky) {
      const float* row = sin_ + (i * 22 + y + ky) * 72 + x4;
      const f32x4 p0 = *reinterpret_cast<const f32x4*>(row);
      const f32x4 p1 = *reinterpret_cast<const f32x4*>(row + 4);
      const f32x2 p2 = *reinterpret_cast<const f32x2*>(row + 8);
      float v[10] = {p0[0], p0[1], p0[2], p0[3], p1[0], p1[1], p1[2], p1[3], p2[0], p2[1]};
      const float* wr = wbase + (i * 7 + ky) * 7;
      #pragma unroll
      for (int kx = 0; kx < 7; ++kx) {
        float wvv = wr[kx];
        a0 += v[kx] * wvv; a1 += v[kx+1] * wvv;
        a2 += v[kx+2] * wvv; a3 += v[kx+3] * wvv;
      }
    }
  }
  u32x2 o;
  o[0] = f2b2(fmaxf((a0 + bia) * inv + shf, 0.f), fmaxf((a1 + bia) * inv + shf, 0.f));
  o[1] = f2b2(fmaxf((a2 + bia) * inv + shf, 0.f), fmaxf((a3 + bia) * inv + shf, 0.f));
  __builtin_nontemporal_store(o, reinterpret_cast<u32x2*>(yo + y * 64 + x4));
}

// ---------------- Kernel D: grouped conv2 + BN + sigmoid gate * x2w (bf16) ----------------
__global__ __launch_bounds__(256) void kd_conv2(
    const u16* __restrict__ y1, const u16* __restrict__ x2w,
    const float* __restrict__ w2, const float* __restrict__ b2,
    const float* __restrict__ g2, const float* __restrict__ bb2,
    const float* __restrict__ m2, const float* __restrict__ v2,
    float* __restrict__ out)
{
  __shared__ float sin_[70 * 72];
  const int bid = blockIdx.x;
  const int wid = (bid & 7) * 256 + (bid >> 3);      // XCD-chunked
  int b = wid >> 6, g = wid & 63;
  const u16* yin = y1 + ((size_t)b * 64 + g) * HW;

  // zero halo: rows 0-2 & 67-69 (full), cols {0,1,2,67,68,69} of rows 3..66
  for (int idx = threadIdx.x; idx < 6 * 72; idx += 256) {
    int r = idx / 72, c = idx - r * 72;
    sin_[(r < 3 ? r : 64 + r) * 72 + c] = 0.f;
  }
  for (int idx = threadIdx.x; idx < 64 * 6; idx += 256) {
    int r = idx / 6, c = idx - r * 6;
    sin_[(r + 3) * 72 + (c < 3 ? c : 64 + c)] = 0.f;
  }
  // interior: uint2 global loads (4 bf16), scalar LDS writes
  for (int idx = threadIdx.x; idx < 64 * 16; idx += 256) {
    int r = idx >> 4, c4 = (idx & 15) * 4;
    uint2 v = *reinterpret_cast<const uint2*>(&yin[r * 64 + c4]);
    float* d = &sin_[(r + 3) * 72 + 3 + c4];
    d[0] = b2f((u16)(v.x & 0xffff)); d[1] = b2f((u16)(v.x >> 16));
    d[2] = b2f((u16)(v.y & 0xffff)); d[3] = b2f((u16)(v.y >> 16));
  }
  __syncthreads();

  float inv[4], shf[4], bia[4];
  #pragma unroll
  for (int i = 0; i < 4; ++i) {
    int n = 4 * g + i;
    float sc = g2[n] / sqrtf(v2[n] + 1e-5f);
    inv[i] = sc; shf[i] = bb2[n] - m2[n] * sc; bia[i] = b2[n];
  }
  const float* wb = w2 + 4 * g * 49;
  const u16* xw = x2w + (size_t)b * 64 * 16384;

  for (int it = 0; it < 4; ++it) {
    int s = it * 256 + threadIdx.x;
    int y = s >> 4, x4 = (s & 15) * 4;
    float acc[4][4] = {};
    #pragma unroll
    for (int ky = 0; ky < 7; ++ky) {
      const float* row = sin_ + (y + ky) * 72 + x4;
      const f32x4 p0 = *reinterpret_cast<const f32x4*>(row);
      const f32x4 p1 = *reinterpret_cast<const f32x4*>(row + 4);
      const f32x2 p2 = *reinterpret_cast<const f32x2*>(row + 8);
      float v[10] = {p0[0], p0[1], p0[2], p0[3], p1[0], p1[1], p1[2], p1[3], p2[0], p2[1]};
      #pragma unroll
      for (int i = 0; i < 4; ++i) {
        const float* wr = wb + i * 49 + ky * 7;
        #pragma unroll
        for (int kx = 0; kx < 7; ++kx) {
          float wvv = wr[kx];
          acc[i][0] += v[kx] * wvv; acc[i][1] += v[kx+1] * wvv;
          acc[i][2] += v[kx+2] * wvv; acc[i][3] += v[kx+3] * wvv;
        }
      }
    }
    int po = y * 64 + x4;
    int wr_ = (y >> 3) * 8 + (x4 >> 3);
    int t0 = (y & 7) * 8 + (x4 & 7);
    const u16* gp = &xw[(size_t)wr_ * 16384 + g * 256 + t0 * 4];
    uint2 q0 = *reinterpret_cast<const uint2*>(gp + 0);
    uint2 q1 = *reinterpret_cast<const uint2*>(gp + 4);
    uint2 q2 = *reinterpret_cast<const uint2*>(gp + 8);
    uint2 q3 = *reinterpret_cast<const uint2*>(gp + 12);
    #pragma unroll
    for (int i = 0; i < 4; ++i) {
      int n = 4 * g + i;
      float* op = out + ((size_t)b * 256 + n) * HW + po;
      float y0 = (acc[i][0] + bia[i]) * inv[i] + shf[i];
      float y1v = (acc[i][1] + bia[i]) * inv[i] + shf[i];
      float y2 = (acc[i][2] + bia[i]) * inv[i] + shf[i];
      float y3 = (acc[i][3] + bia[i]) * inv[i] + shf[i];
      float g0 = b2f((u16)(i < 2 ? (q0.x >> (16 * i)) : (q0.y >> (16 * (i - 2)))));
      float g1v = b2f((u16)(i < 2 ? (q1.x >> (16 * i)) : (q1.y >> (16 * (i - 2)))));
      float g2v = b2f((u16)(i < 2 ? (q2.x >> (16 * i)) : (q2.y >> (16 * (i - 2)))));
      float g3 = b2f((u16)(i < 2 ? (q3.x >> (16 * i)) : (q3.y >> (16 * (i - 2)))));
      float4 r;
      r.x = g0  / (1.f + __expf(-y0));
      r.y = g1v / (1.f + __expf(-y1v));
      r.z = g2v / (1.f + __expf(-y2));
      r.w = g3  / (1.f + __expf(-y3));
      nt_store4(r, op);
    }
  }
}

extern "C" void kernel_launch(void* const* d_in, const int* in_sizes, int n_in,
                              void* d_out, int out_size, void* d_ws, size_t ws_size,
                              hipStream_t stream) {
  const float* x     = (const float*)d_in[0];
  const float* qkv_w = (const float*)d_in[1];
  const float* qkv_b = (const float*)d_in[2];
  const float* out_w = (const float*)d_in[3];
  const float* out_b = (const float*)d_in[4];
  const float* ca_w1 = (const float*)d_in[5];
  const float* ca_b1 = (const float*)d_in[6];
  const float* ca_w2 = (const float*)d_in[7];
  const float* ca_b2 = (const float*)d_in[8];
  const float* sa_w1 = (const float*)d_in[9];
  const float* sa_b1 = (const float*)d_in[10];
  const float* bn1_g = (const float*)d_in[11];
  const float* bn1_b = (const float*)d_in[12];
  const float* bn1_m = (const float*)d_in[13];
  const float* bn1_v = (const float*)d_in[14];
  const float* sa_w2 = (const float*)d_in[15];
  const float* sa_b2 = (const float*)d_in[16];
  const float* bn2_g = (const float*)d_in[17];
  const float* bn2_b = (const float*)d_in[18];
  const float* bn2_m = (const float*)d_in[19];
  const float* bn2_v = (const float*)d_in[20];

  float* outp = (float*)d_out;
  u16* x2w = (u16*)d_ws;                            // [win][cq][tok][quad] bf16, 64 MB
  u16* y1 = x2w + (size_t)2048 * 16384;             // conv1 output bf16, 16 MB

  // bf16 weights + O buffer stashed in d_out (overwritten by kd at the end)
  u16* wq2 = (u16*)d_out;                           // 196608
  u16* wo2 = wq2 + 48 * 8 * 512;                    // 65536
  u16* c1f = wo2 + 16 * 8 * 512;                    // 16384
  u16* c2f = c1f + 4 * 8 * 512;                     // 16384
  u16* Og  = c2f + 16 * 2 * 512;                    // 2048*16384 u16 = 64 MB

  kprep   <<<768,  256, 0, stream>>>(qkv_w, out_w, ca_w1, ca_w2, wq2, wo2, c1f, c2f);
  kb_attn <<<2048, 256, 0, stream>>>(x, x2w, Og, wq2, qkv_b, out_b, c1f, ca_b1, c2f, ca_b2);
  kb_oproj<<<2048, 256, 0, stream>>>(Og, wo2, x2w);
  kc_conv1<<<8192, 256, 0, stream>>>(x2w, sa_w1, sa_b1, bn1_g, bn1_b, bn1_m, bn1_v, y1);
  kd_conv2<<<2048, 256, 0, stream>>>(y1, x2w, sa_w2, sa_b2, bn2_g, bn2_b, bn2_m, bn2_v, outp);
}